// Round 2
// baseline (115.960 us; speedup 1.0000x reference)
//
#include <hip/hip_runtime.h>
#include <hip/hip_bf16.h>

typedef __attribute__((ext_vector_type(8))) short bf16x8;   // 8 bf16 (MFMA A/B frag)
typedef __attribute__((ext_vector_type(4))) float f32x4;    // MFMA C/D frag

static __device__ __forceinline__ unsigned short f2b(float f) {
  union { __hip_bfloat16 h; unsigned short u; } cv;
  cv.h = __float2bfloat16(f);
  return cv.u;
}

static __device__ __forceinline__ bf16x8 pack8(float4 a, float4 b) {
  bf16x8 r;
  r[0] = (short)f2b(a.x); r[1] = (short)f2b(a.y); r[2] = (short)f2b(a.z); r[3] = (short)f2b(a.w);
  r[4] = (short)f2b(b.x); r[5] = (short)f2b(b.y); r[6] = (short)f2b(b.z); r[7] = (short)f2b(b.w);
  return r;
}

// ---------------- prep: weights -> bf16 W^T in ws ----------------
// wt layout (bf16 elems): WT1 @0 (256x128), WT2 @32768 (256x256), WT3 @98304 (256x256)
__global__ void __launch_bounds__(256) gnn_prep(const float* __restrict__ W1,
                                                const float* __restrict__ W2,
                                                const float* __restrict__ W3,
                                                unsigned short* __restrict__ wt) {
  int idx = blockIdx.x * 256 + threadIdx.x;   // 0..65535
  unsigned short* wt1 = wt;
  unsigned short* wt2 = wt + 32768;
  unsigned short* wt3 = wt + 98304;
  if (idx < 32768) { int d = idx >> 8, h = idx & 255; wt1[h * 128 + d] = f2b(W1[idx]); }
  { int d = idx >> 8, h = idx & 255; wt2[h * 256 + d] = f2b(W2[idx]); wt3[h * 256 + d] = f2b(W3[idx]); }
}

// ---------------- prep: X [g][j][d] fp32 -> X^T [g][d][j] bf16 in ws ----------------
// 4x4 register-blocked transpose; LDS XOR-swizzled (granule ^= (d>>2)&15) so both the
// 8B transposed writes (~2-way) and the b128 row reads (full-row) are conflict-light.
__global__ void __launch_bounds__(256) tp_x(const float* __restrict__ xin,
                                            unsigned short* __restrict__ xt0) {
  __shared__ unsigned short sT[128 * 128];
  int g = blockIdx.x, t = threadIdx.x;
  const float* xg = xin + (size_t)g * 16384;
#pragma unroll
  for (int v = 0; v < 4; ++v) {
    int bi = v * 256 + t;
    int db = bi & 31, jb = bi >> 5;       // lanes vary db -> coalesced reads, spread writes
    int j0 = jb * 4, d0 = db * 4;
    float4 r0 = *(const float4*)(xg + (j0 + 0) * 128 + d0);
    float4 r1 = *(const float4*)(xg + (j0 + 1) * 128 + d0);
    float4 r2 = *(const float4*)(xg + (j0 + 2) * 128 + d0);
    float4 r3 = *(const float4*)(xg + (j0 + 3) * 128 + d0);
    int coff = ((jb * 8) ^ ((db & 15) << 4)) >> 1;   // swizzled ushort col offset
    *(ushort4*)&sT[(d0 + 0) * 128 + coff] = make_ushort4(f2b(r0.x), f2b(r1.x), f2b(r2.x), f2b(r3.x));
    *(ushort4*)&sT[(d0 + 1) * 128 + coff] = make_ushort4(f2b(r0.y), f2b(r1.y), f2b(r2.y), f2b(r3.y));
    *(ushort4*)&sT[(d0 + 2) * 128 + coff] = make_ushort4(f2b(r0.z), f2b(r1.z), f2b(r2.z), f2b(r3.z));
    *(ushort4*)&sT[(d0 + 3) * 128 + coff] = make_ushort4(f2b(r0.w), f2b(r1.w), f2b(r2.w), f2b(r3.w));
  }
  __syncthreads();
  unsigned short* og = xt0 + (size_t)g * 16384;
#pragma unroll
  for (int it = 0; it < 8; ++it) {
    int e = it * 2048 + t * 8;
    int d = e >> 7, j0 = e & 127;
    int cidx = ((j0 * 2) ^ (((d >> 2) & 15) << 4)) >> 1;
    *(bf16x8*)(og + e) = *(const bf16x8*)&sT[d * 128 + cidx];   // natural [d][j] out
  }
}

// ---------------- main: one block per graph, 512 thr, 80 KB LDS -> 2 blocks/CU ----------------
// sXT byte-swizzle: 16B granule ^= (d&15); sAggC: granule ^= (i&7). Same XOR on write+read.
#define XS(d, colb) ((d) * 128 + ((((colb)) ^ (((d) & 15) << 4)) >> 1))
#define AGS(i, colb) ((i) * 64 + ((((colb)) ^ (((i) & 7) << 4)) >> 1))

__global__ void __launch_bounds__(512, 4) gnn_main(
    const float* __restrict__ adjg,
    const float* __restrict__ b1, const float* __restrict__ b2,
    const float* __restrict__ b3, const float* __restrict__ Wh,
    const float* __restrict__ bh, const unsigned short* __restrict__ xt0,
    const unsigned short* __restrict__ wt, float* __restrict__ out) {
  __shared__ unsigned short sXT[256 * 128];    // X^T [d][j], swizzled; 64 KB
  __shared__ unsigned short sAggC[128 * 64];   // AGG chunk [i][dloc], swizzled; 16 KB

  const int g = blockIdx.x, tid = threadIdx.x;
  const int lane = tid & 63, w = tid >> 6;
  const int l15 = lane & 15, l4 = lane >> 4;
  const int wm = w & 1, wn = w >> 1;

  const float* ag = adjg + (size_t)g * 16384;
  const unsigned short* xg = xt0 + (size_t)g * 16384;

  // ---- adj B-fragments: identical for every chunk AND layer -> load once, hold in regs ----
  float4 araw[2][4][2];
#pragma unroll
  for (int ni = 0; ni < 2; ++ni) {
    int ir = wn * 32 + ni * 16 + l15;
#pragma unroll
    for (int ks = 0; ks < 4; ++ks) {
      araw[ni][ks][0] = *(const float4*)(ag + ir * 128 + ks * 32 + l4 * 8);
      araw[ni][ks][1] = *(const float4*)(ag + ir * 128 + ks * 32 + l4 * 8 + 4);
    }
  }
  // ---- stage layer-1 X^T (32 KB, linear copy + swizzle at LDS write: conflict-free) ----
#pragma unroll
  for (int it = 0; it < 4; ++it) {
    int off = it * 8192 + tid * 16;      // byte offset in [0, 32768)
    int row = off >> 8, colb = off & 255;
    *(bf16x8*)&sXT[XS(row, colb)] = *(const bf16x8*)(xg + (off >> 1));
  }
  bf16x8 adjF[2][4];
#pragma unroll
  for (int ni = 0; ni < 2; ++ni)
#pragma unroll
    for (int ks = 0; ks < 4; ++ks)
      adjF[ni][ks] = pack8(araw[ni][ks][0], araw[ni][ks][1]);
  __syncthreads();

  f32x4 accB[4][4];

  for (int l = 0; l < 3; ++l) {
    const int Din = (l == 0) ? 128 : 256;
    const int nck = Din >> 6;
    const unsigned short* wtl = (l == 0) ? wt : (l == 1) ? wt + 32768 : wt + 98304;
    const float* bl = (l == 0) ? b1 : (l == 1) ? b2 : b3;
    float bias[4];
#pragma unroll
    for (int ni = 0; ni < 4; ++ni) bias[ni] = bl[wn * 64 + ni * 16 + l15];

#pragma unroll
    for (int mi = 0; mi < 4; ++mi)
#pragma unroll
      for (int ni = 0; ni < 4; ++ni) accB[mi][ni] = (f32x4){0.f, 0.f, 0.f, 0.f};

    for (int c = 0; c < nck; ++c) {
      // ---- phase A': AGGT[d-chunk][i] = sum_j XT[d][j] * adj[j][i]  (adj symmetric) ----
      f32x4 accA[2][2];
#pragma unroll
      for (int mi = 0; mi < 2; ++mi)
#pragma unroll
        for (int ni = 0; ni < 2; ++ni) accA[mi][ni] = (f32x4){0.f, 0.f, 0.f, 0.f};
#pragma unroll
      for (int ks = 0; ks < 4; ++ks) {
        bf16x8 a[2];
#pragma unroll
        for (int mi = 0; mi < 2; ++mi) {
          int dr = c * 64 + wm * 32 + mi * 16 + l15;
          a[mi] = *(const bf16x8*)&sXT[XS(dr, ks * 64 + l4 * 16)];
        }
#pragma unroll
        for (int mi = 0; mi < 2; ++mi)
#pragma unroll
          for (int ni = 0; ni < 2; ++ni)
            accA[mi][ni] = __builtin_amdgcn_mfma_f32_16x16x32_bf16(a[mi], adjF[ni][ks], accA[mi][ni], 0, 0, 0);
      }
      // ---- W fragments for phase B: direct from L2-hot ws; latency spans store+barrier ----
      bf16x8 wf[2][4];
#pragma unroll
      for (int ks = 0; ks < 2; ++ks)
#pragma unroll
        for (int ni = 0; ni < 4; ++ni) {
          int hr = wn * 64 + ni * 16 + l15;
          wf[ks][ni] = *(const bf16x8*)(wtl + hr * Din + c * 64 + ks * 32 + l4 * 8);
        }
      // ---- store AGG chunk (8B swizzled writes) ----
#pragma unroll
      for (int mi = 0; mi < 2; ++mi)
#pragma unroll
        for (int ni = 0; ni < 2; ++ni) {
          int dloc = wm * 32 + mi * 16 + l4 * 4;
          int i = wn * 32 + ni * 16 + l15;
          f32x4 v = accA[mi][ni];
          *(ushort4*)&sAggC[AGS(i, 2 * dloc)] =
              make_ushort4(f2b(v[0]), f2b(v[1]), f2b(v[2]), f2b(v[3]));
        }
      __syncthreads();
      // ---- phase B: accB += AGG_chunk @ W_chunk ----
#pragma unroll
      for (int ks = 0; ks < 2; ++ks) {
        bf16x8 a[4];
#pragma unroll
        for (int mi = 0; mi < 4; ++mi) {
          int ir = wm * 64 + mi * 16 + l15;
          a[mi] = *(const bf16x8*)&sAggC[AGS(ir, ks * 64 + l4 * 16)];
        }
#pragma unroll
        for (int mi = 0; mi < 4; ++mi)
#pragma unroll
          for (int ni = 0; ni < 4; ++ni)
            accB[mi][ni] = __builtin_amdgcn_mfma_f32_16x16x32_bf16(a[mi], wf[ks][ni], accB[mi][ni], 0, 0, 0);
      }
      __syncthreads();
    } // chunks

    if (l < 2) {
      // H[i][h] -> sXT[h][i] (next layer's X^T), contiguous 8B swizzled writes
#pragma unroll
      for (int ni = 0; ni < 4; ++ni) {
        int h = wn * 64 + ni * 16 + l15;
#pragma unroll
        for (int mi = 0; mi < 4; ++mi) {
          int i0 = wm * 64 + mi * 16 + l4 * 4;
          f32x4 v = accB[mi][ni];
          *(ushort4*)&sXT[XS(h, 2 * i0)] = make_ushort4(
              f2b(fmaxf(v[0] + bias[ni], 0.f)), f2b(fmaxf(v[1] + bias[ni], 0.f)),
              f2b(fmaxf(v[2] + bias[ni], 0.f)), f2b(fmaxf(v[3] + bias[ni], 0.f)));
        }
      }
      __syncthreads();
    } else {
      // ---- mean pool + linear head (fp32) ----
      float* sPool = (float*)sAggC;
      float ps[4];
#pragma unroll
      for (int ni = 0; ni < 4; ++ni) {
        float s = 0.f;
#pragma unroll
        for (int mi = 0; mi < 4; ++mi)
#pragma unroll
          for (int r = 0; r < 4; ++r) s += fmaxf(accB[mi][ni][r] + bias[ni], 0.f);
        s += __shfl_xor(s, 16);
        s += __shfl_xor(s, 32);
        ps[ni] = s;
      }
      if (l4 == 0) {
#pragma unroll
        for (int ni = 0; ni < 4; ++ni) sPool[wm * 256 + wn * 64 + ni * 16 + l15] = ps[ni];
      }
      __syncthreads();
      if (w == 0) {
        float acc = 0.f;
#pragma unroll
        for (int q = 0; q < 4; ++q) {
          int h = lane + q * 64;
          acc += (sPool[h] + sPool[256 + h]) * Wh[h];
        }
#pragma unroll
        for (int off = 32; off > 0; off >>= 1) acc += __shfl_xor(acc, off);
        if (lane == 0) out[g] = acc * (1.0f / 128.0f) + bh[0];
      }
    }
  }
}

extern "C" void kernel_launch(void* const* d_in, const int* in_sizes, int n_in,
                              void* d_out, int out_size, void* d_ws, size_t ws_size,
                              hipStream_t stream) {
  const float* xin = (const float*)d_in[0];   // node_features [512,128,128]
  const float* adj = (const float*)d_in[1];   // adj [512,128,128]
  const float* W1  = (const float*)d_in[2];
  const float* b1  = (const float*)d_in[3];
  const float* W2  = (const float*)d_in[4];
  const float* b2  = (const float*)d_in[5];
  const float* W3  = (const float*)d_in[6];
  const float* b3  = (const float*)d_in[7];
  const float* Wh  = (const float*)d_in[8];
  const float* bh  = (const float*)d_in[9];

  unsigned short* xt0 = (unsigned short*)d_ws;          // 512*16384 bf16 = 16.78 MB
  unsigned short* wt  = xt0 + (size_t)512 * 16384;      // +329,728 B of W^T

  tp_x<<<512, 256, 0, stream>>>(xin, xt0);
  gnn_prep<<<256, 256, 0, stream>>>(W1, W2, W3, wt);
  gnn_main<<<512, 512, 0, stream>>>(adj, b1, b2, b3, Wh, bh, xt0, wt, (float*)d_out);
}

// Round 3
// 78.326 us; speedup vs baseline: 1.4805x; 1.4805x over previous
//
#include <hip/hip_runtime.h>
#include <hip/hip_bf16.h>

typedef __attribute__((ext_vector_type(8))) short bf16x8;   // 8 bf16 (MFMA A/B frag)
typedef __attribute__((ext_vector_type(4))) float f32x4;    // MFMA C/D frag

static __device__ __forceinline__ unsigned short f2b(float f) {
  union { __hip_bfloat16 h; unsigned short u; } cv;
  cv.h = __float2bfloat16(f);
  return cv.u;
}

static __device__ __forceinline__ bf16x8 pack8(float4 a, float4 b) {
  bf16x8 r;
  r[0] = (short)f2b(a.x); r[1] = (short)f2b(a.y); r[2] = (short)f2b(a.z); r[3] = (short)f2b(a.w);
  r[4] = (short)f2b(b.x); r[5] = (short)f2b(b.y); r[6] = (short)f2b(b.z); r[7] = (short)f2b(b.w);
  return r;
}

// ---- prep: X [g][j][d] fp32 -> X^T [g][d][j] bf16 in ws; also weights -> bf16 W^T ----
// wt layout (bf16 elems): WT1 @0 (256x128), WT2 @32768 (256x256), WT3 @98304 (256x256)
__global__ void __launch_bounds__(256) tp_x(const float* __restrict__ xin,
                                            unsigned short* __restrict__ xt0,
                                            const float* __restrict__ W1,
                                            const float* __restrict__ W2,
                                            const float* __restrict__ W3,
                                            unsigned short* __restrict__ wt) {
  __shared__ unsigned short sT[128 * 128];
  int g = blockIdx.x, t = threadIdx.x;
  const float* xg = xin + (size_t)g * 16384;
#pragma unroll
  for (int v = 0; v < 4; ++v) {
    int bi = v * 256 + t;
    int db = bi & 31, jb = bi >> 5;
    int j0 = jb * 4, d0 = db * 4;
    float4 r0 = *(const float4*)(xg + (j0 + 0) * 128 + d0);
    float4 r1 = *(const float4*)(xg + (j0 + 1) * 128 + d0);
    float4 r2 = *(const float4*)(xg + (j0 + 2) * 128 + d0);
    float4 r3 = *(const float4*)(xg + (j0 + 3) * 128 + d0);
    int coff = ((jb * 8) ^ ((db & 15) << 4)) >> 1;   // swizzled ushort col offset
    *(ushort4*)&sT[(d0 + 0) * 128 + coff] = make_ushort4(f2b(r0.x), f2b(r1.x), f2b(r2.x), f2b(r3.x));
    *(ushort4*)&sT[(d0 + 1) * 128 + coff] = make_ushort4(f2b(r0.y), f2b(r1.y), f2b(r2.y), f2b(r3.y));
    *(ushort4*)&sT[(d0 + 2) * 128 + coff] = make_ushort4(f2b(r0.z), f2b(r1.z), f2b(r2.z), f2b(r3.z));
    *(ushort4*)&sT[(d0 + 3) * 128 + coff] = make_ushort4(f2b(r0.w), f2b(r1.w), f2b(r2.w), f2b(r3.w));
  }
  // weight prep folded in (task T: [0,32768) W1, [32768,98304) W2, [98304,163840) W3)
  {
    int T = g * 256 + t;                 // 0..131071
    unsigned short* wt1 = wt;
    unsigned short* wt2 = wt + 32768;
    unsigned short* wt3 = wt + 98304;
    if (T < 32768) {
      int d = T >> 8, h = T & 255;
      wt1[h * 128 + d] = f2b(W1[T]);
      int i3 = T + 32768;                // W3 second half via T+131072 - 98304
      int d3 = i3 >> 8, h3 = i3 & 255;
      wt3[h3 * 256 + d3] = f2b(W3[i3]);
    } else if (T < 98304) {
      int i2 = T - 32768;
      int d = i2 >> 8, h = i2 & 255;
      wt2[h * 256 + d] = f2b(W2[i2]);
    } else {
      int i3 = T - 98304;                // W3 first half
      int d = i3 >> 8, h = i3 & 255;
      wt3[h * 256 + d] = f2b(W3[i3]);
    }
  }
  __syncthreads();
  unsigned short* og = xt0 + (size_t)g * 16384;
#pragma unroll
  for (int it = 0; it < 8; ++it) {
    int e = it * 2048 + t * 8;
    int d = e >> 7, j0 = e & 127;
    int cidx = ((j0 * 2) ^ (((d >> 2) & 15) << 4)) >> 1;
    *(bf16x8*)(og + e) = *(const bf16x8*)&sT[d * 128 + cidx];
  }
}

// ---- main: one block per graph, 512 thr, 80 KB LDS + <=128 VGPR -> 2 blocks/CU ----
// sXT byte-swizzle: 16B granule ^= (d&15); sAggC: granule ^= (i&7). Same XOR write+read.
#define XS(d, colb) ((d) * 128 + ((((colb)) ^ (((d) & 15) << 4)) >> 1))
#define AGS(i, colb) ((i) * 64 + ((((colb)) ^ (((i) & 7) << 4)) >> 1))

__global__ void __launch_bounds__(512, 4) gnn_main(
    const float* __restrict__ adjg,
    const float* __restrict__ b1, const float* __restrict__ b2,
    const float* __restrict__ b3, const float* __restrict__ Wh,
    const float* __restrict__ bh, const unsigned short* __restrict__ xt0,
    const unsigned short* __restrict__ wt, float* __restrict__ out) {
  __shared__ unsigned short sXT[256 * 128];    // X^T [d][j], swizzled; 64 KB
  __shared__ unsigned short sAggC[128 * 64];   // AGG chunk [i][dloc], swizzled; 16 KB

  const int g = blockIdx.x, tid = threadIdx.x;
  const int lane = tid & 63, w = tid >> 6;
  const int l15 = lane & 15, l4 = lane >> 4;
  const int wm = w & 1, wn = w >> 1;

  const float* ag = adjg + (size_t)g * 16384;
  const unsigned short* xg = xt0 + (size_t)g * 16384;

  // ---- adj B-fragments (A-phase grid 1x8: wave w owns i in [w*16, w*16+16)) ----
  // loaded ONCE, packed to 16 persistent VGPRs; transient fp32 regs die before accB lives
  bf16x8 adjF[4];
  {
    int ir = w * 16 + l15;
#pragma unroll
    for (int ks = 0; ks < 4; ++ks) {
      float4 a0 = *(const float4*)(ag + ir * 128 + ks * 32 + l4 * 8);
      float4 a1 = *(const float4*)(ag + ir * 128 + ks * 32 + l4 * 8 + 4);
      adjF[ks] = pack8(a0, a1);
    }
  }
  // ---- stage layer-1 X^T (32 KB linear copy, swizzle applied at LDS write) ----
#pragma unroll
  for (int it = 0; it < 4; ++it) {
    int off = it * 8192 + tid * 16;      // byte offset in [0, 32768)
    int row = off >> 8, colb = off & 255;
    *(bf16x8*)&sXT[XS(row, colb)] = *(const bf16x8*)(xg + (off >> 1));
  }
  __syncthreads();

  f32x4 accB[4][4];

  for (int l = 0; l < 3; ++l) {
    const int Din = (l == 0) ? 128 : 256;
    const int nck = Din >> 6;
    const unsigned short* wtl = (l == 0) ? wt : (l == 1) ? wt + 32768 : wt + 98304;
    const float* bl = (l == 0) ? b1 : (l == 1) ? b2 : b3;
    float bias[4];
#pragma unroll
    for (int ni = 0; ni < 4; ++ni) bias[ni] = bl[wn * 64 + ni * 16 + l15];

#pragma unroll
    for (int mi = 0; mi < 4; ++mi)
#pragma unroll
      for (int ni = 0; ni < 4; ++ni) accB[mi][ni] = (f32x4){0.f, 0.f, 0.f, 0.f};

    for (int c = 0; c < nck; ++c) {
      // ---- phase A': AGGT[dloc][i] = sum_j XT[c*64+dloc][j] * adj[j][i], mi in halves ----
#pragma unroll
      for (int h2 = 0; h2 < 2; ++h2) {
        f32x4 accA[2];
        accA[0] = (f32x4){0.f, 0.f, 0.f, 0.f};
        accA[1] = (f32x4){0.f, 0.f, 0.f, 0.f};
#pragma unroll
        for (int ks = 0; ks < 4; ++ks) {
          bf16x8 a[2];
#pragma unroll
          for (int mi = 0; mi < 2; ++mi) {
            int dr = c * 64 + h2 * 32 + mi * 16 + l15;
            a[mi] = *(const bf16x8*)&sXT[XS(dr, ks * 64 + l4 * 16)];
          }
#pragma unroll
          for (int mi = 0; mi < 2; ++mi)
            accA[mi] = __builtin_amdgcn_mfma_f32_16x16x32_bf16(a[mi], adjF[ks], accA[mi], 0, 0, 0);
        }
#pragma unroll
        for (int mi = 0; mi < 2; ++mi) {
          int dloc = h2 * 32 + mi * 16 + l4 * 4;
          int i = w * 16 + l15;
          f32x4 v = accA[mi];
          *(ushort4*)&sAggC[AGS(i, 2 * dloc)] =
              make_ushort4(f2b(v[0]), f2b(v[1]), f2b(v[2]), f2b(v[3]));
        }
      }
      __syncthreads();
      // ---- phase B: accB += AGG_chunk @ W_chunk (W frags per-ks from L2-hot ws) ----
#pragma unroll
      for (int ks = 0; ks < 2; ++ks) {
        bf16x8 aB[4], wf[4];
#pragma unroll
        for (int mi = 0; mi < 4; ++mi) {
          int ir = wm * 64 + mi * 16 + l15;
          aB[mi] = *(const bf16x8*)&sAggC[AGS(ir, ks * 64 + l4 * 16)];
        }
#pragma unroll
        for (int ni = 0; ni < 4; ++ni) {
          int hr = wn * 64 + ni * 16 + l15;
          wf[ni] = *(const bf16x8*)(wtl + hr * Din + c * 64 + ks * 32 + l4 * 8);
        }
#pragma unroll
        for (int mi = 0; mi < 4; ++mi)
#pragma unroll
          for (int ni = 0; ni < 4; ++ni)
            accB[mi][ni] = __builtin_amdgcn_mfma_f32_16x16x32_bf16(aB[mi], wf[ni], accB[mi][ni], 0, 0, 0);
      }
      __syncthreads();
    } // chunks

    if (l < 2) {
      // H[i][h] -> sXT[h][i] (next layer's X^T), 8B swizzled writes
#pragma unroll
      for (int ni = 0; ni < 4; ++ni) {
        int h = wn * 64 + ni * 16 + l15;
#pragma unroll
        for (int mi = 0; mi < 4; ++mi) {
          int i0 = wm * 64 + mi * 16 + l4 * 4;
          f32x4 v = accB[mi][ni];
          *(ushort4*)&sXT[XS(h, 2 * i0)] = make_ushort4(
              f2b(fmaxf(v[0] + bias[ni], 0.f)), f2b(fmaxf(v[1] + bias[ni], 0.f)),
              f2b(fmaxf(v[2] + bias[ni], 0.f)), f2b(fmaxf(v[3] + bias[ni], 0.f)));
        }
      }
      __syncthreads();
    } else {
      // ---- mean pool + linear head (fp32) ----
      float* sPool = (float*)sAggC;
      float ps[4];
#pragma unroll
      for (int ni = 0; ni < 4; ++ni) {
        float s = 0.f;
#pragma unroll
        for (int mi = 0; mi < 4; ++mi)
#pragma unroll
          for (int r = 0; r < 4; ++r) s += fmaxf(accB[mi][ni][r] + bias[ni], 0.f);
        s += __shfl_xor(s, 16);
        s += __shfl_xor(s, 32);
        ps[ni] = s;
      }
      if (l4 == 0) {
#pragma unroll
        for (int ni = 0; ni < 4; ++ni) sPool[wm * 256 + wn * 64 + ni * 16 + l15] = ps[ni];
      }
      __syncthreads();
      if (w == 0) {
        float acc = 0.f;
#pragma unroll
        for (int q = 0; q < 4; ++q) {
          int h = lane + q * 64;
          acc += (sPool[h] + sPool[256 + h]) * Wh[h];
        }
#pragma unroll
        for (int off = 32; off > 0; off >>= 1) acc += __shfl_xor(acc, off);
        if (lane == 0) out[g] = acc * (1.0f / 128.0f) + bh[0];
      }
    }
  }
}

extern "C" void kernel_launch(void* const* d_in, const int* in_sizes, int n_in,
                              void* d_out, int out_size, void* d_ws, size_t ws_size,
                              hipStream_t stream) {
  const float* xin = (const float*)d_in[0];   // node_features [512,128,128]
  const float* adj = (const float*)d_in[1];   // adj [512,128,128]
  const float* W1  = (const float*)d_in[2];
  const float* b1  = (const float*)d_in[3];
  const float* W2  = (const float*)d_in[4];
  const float* b2  = (const float*)d_in[5];
  const float* W3  = (const float*)d_in[6];
  const float* b3  = (const float*)d_in[7];
  const float* Wh  = (const float*)d_in[8];
  const float* bh  = (const float*)d_in[9];

  unsigned short* xt0 = (unsigned short*)d_ws;          // 512*16384 bf16 = 16.78 MB
  unsigned short* wt  = xt0 + (size_t)512 * 16384;      // +327,680 B of W^T

  tp_x<<<512, 256, 0, stream>>>(xin, xt0, W1, W2, W3, wt);
  gnn_main<<<512, 512, 0, stream>>>(adj, b1, b2, b3, Wh, bh, xt0, wt, (float*)d_out);
}